// Round 1
// baseline (887.046 us; speedup 1.0000x reference)
//
#include <hip/hip_runtime.h>
#include <stdint.h>

// JAX >= 0.4.36 defaults to jax_threefry_partitionable=True. If bench shows
// absmax ~= 1.0 (RNG stream mismatch), flip this to 0 (legacy paired scheme).
#define THREEFRY_PARTITIONABLE 1

#define B_SZ 32
#define T_SZ 300
#define F_IN 3072
#define F_HID 410
#define F_OUT 10
#define M_SZ (B_SZ * T_SZ)              // 9600
#define N_PAD 512                       // padded hidden width
#define KW (F_IN / 32)                  // 96 bit-words per spike row
#define TOTAL_ELEMS (B_SZ * T_SZ * F_IN)  // 29491200
#define HALF_N (TOTAL_ELEMS / 2)          // 14745600
#define N_WORDS (TOTAL_ELEMS / 32)        // 921600
#define A2_STRIDE 16

// f32(exp(f32(-0.1))) — PSP decay, matches XLA's correctly-rounded exp
#define DECAY 0.90483741803595957f
#define THETA 10.0f

__device__ __forceinline__ uint32_t rotl32(uint32_t x, uint32_t r) {
  return (x << r) | (x >> (32u - r));
}

// JAX threefry2x32, key = (0, 42)  [jax.random.key(42) -> (hi,lo)=(0,42)]
__device__ __forceinline__ void threefry2x32(uint32_t& x0, uint32_t& x1) {
  const uint32_t ks0 = 0u;
  const uint32_t ks1 = 42u;
  const uint32_t ks2 = 0x1BD11BDAu ^ 0u ^ 42u;
  x0 += ks0; x1 += ks1;
#define TF_ROUND(r) { x0 += x1; x1 = rotl32(x1, (r)); x1 ^= x0; }
  TF_ROUND(13) TF_ROUND(15) TF_ROUND(26) TF_ROUND(6)
  x0 += ks1; x1 += ks2 + 1u;
  TF_ROUND(17) TF_ROUND(29) TF_ROUND(16) TF_ROUND(24)
  x0 += ks2; x1 += ks0 + 2u;
  TF_ROUND(13) TF_ROUND(15) TF_ROUND(26) TF_ROUND(6)
  x0 += ks0; x1 += ks1 + 3u;
  TF_ROUND(17) TF_ROUND(29) TF_ROUND(16) TF_ROUND(24)
  x0 += ks1; x1 += ks2 + 4u;
  TF_ROUND(13) TF_ROUND(15) TF_ROUND(26) TF_ROUND(6)
  x0 += ks2; x1 += ks0 + 5u;
#undef TF_ROUND
}

// JAX uniform [0,1): bitcast(bits>>9 | 0x3F800000) - 1.0f
__device__ __forceinline__ float u01(uint32_t bits) {
  return __uint_as_float((bits >> 9) | 0x3F800000u) - 1.0f;
}

#if THREEFRY_PARTITIONABLE
// One thread per 32-bit output word (32 consecutive flat indices, same (b, f-chunk)).
// Partitionable scheme: ctr = (0, i), bits = o0 ^ o1.
__global__ __launch_bounds__(256) void rng_spikes(const float* __restrict__ inp,
                                                  uint32_t* __restrict__ sbits) {
  uint32_t j = blockIdx.x * 256u + threadIdx.x;  // [0, 921600)
  uint32_t base = j << 5;
  uint32_t b = base / (uint32_t)(T_SZ * F_IN);
  uint32_t f = base % (uint32_t)F_IN;            // 32 | 3072: no row crossing
  const float* p = inp + b * F_IN + f;
  float pr[32];
#pragma unroll
  for (int q = 0; q < 8; ++q) {
    float4 v = ((const float4*)p)[q];
    pr[q * 4 + 0] = v.x; pr[q * 4 + 1] = v.y; pr[q * 4 + 2] = v.z; pr[q * 4 + 3] = v.w;
  }
  uint32_t w = 0u;
#pragma unroll
  for (uint32_t k = 0; k < 32u; ++k) {
    uint32_t x0 = 0u, x1 = base + k;
    threefry2x32(x0, x1);
    float u = u01(x0 ^ x1);
    w |= (u < pr[k]) ? (1u << k) : 0u;
  }
  sbits[j] = w;
}
#else
// Legacy scheme: counts split in halves; pair i -> (ctr0=i, ctr1=i+HALF_N),
// out[i] = o0, out[i+HALF_N] = o1. One thread per 32 pairs -> 2 words.
__global__ __launch_bounds__(256) void rng_spikes(const float* __restrict__ inp,
                                                  uint32_t* __restrict__ sbits) {
  uint32_t j = blockIdx.x * 256u + threadIdx.x;  // [0, 460800)
  uint32_t base = j << 5;
  uint32_t b0 = base / (uint32_t)(T_SZ * F_IN);
  uint32_t f = base % (uint32_t)F_IN;
  const float* p0 = inp + b0 * F_IN + f;
  const float* p1 = inp + (b0 + 16) * F_IN + f;  // HALF_N = 16 batches exactly
  float pa[32], pb[32];
#pragma unroll
  for (int q = 0; q < 8; ++q) {
    float4 va = ((const float4*)p0)[q];
    float4 vb = ((const float4*)p1)[q];
    pa[q * 4 + 0] = va.x; pa[q * 4 + 1] = va.y; pa[q * 4 + 2] = va.z; pa[q * 4 + 3] = va.w;
    pb[q * 4 + 0] = vb.x; pb[q * 4 + 1] = vb.y; pb[q * 4 + 2] = vb.z; pb[q * 4 + 3] = vb.w;
  }
  uint32_t w0 = 0u, w1 = 0u;
#pragma unroll
  for (uint32_t k = 0; k < 32u; ++k) {
    uint32_t x0 = base + k, x1 = base + k + (uint32_t)HALF_N;
    threefry2x32(x0, x1);
    w0 |= (u01(x0) < pa[k]) ? (1u << k) : 0u;
    w1 |= (u01(x1) < pb[k]) ? (1u << k) : 0u;
  }
  sbits[j] = w0;
  sbits[(uint32_t)(HALF_N / 32) + j] = w1;
}
#endif

// Wt[k][o] = (o < 410) ? W1[o][k] : 0   — k-major for coalesced GEMM staging
__global__ __launch_bounds__(256) void transpose_w1(const float* __restrict__ W1,
                                                    float* __restrict__ Wt) {
  __shared__ float tile[32][33];
  int tx = threadIdx.x & 31;
  int ty = threadIdx.x >> 5;  // 0..7
  int kb = blockIdx.x * 32;   // 96 tiles
  int ob = blockIdx.y * 32;   // 16 tiles (covers pad to 512)
#pragma unroll
  for (int r = 0; r < 32; r += 8) {
    int o = ob + ty + r;
    tile[ty + r][tx] = (o < F_HID) ? W1[o * F_IN + kb + tx] : 0.0f;
  }
  __syncthreads();
#pragma unroll
  for (int r = 0; r < 32; r += 8) {
    Wt[(kb + ty + r) * N_PAD + ob + tx] = tile[tx][ty + r];
  }
}

// a1[m][o] = sum_f spike(m,f) * W1[o][f].  A = bitpacked spikes (registers),
// B = Wt tile via LDS. 64x64 tile, 1 wave/block, 8x8 micro-tile.
__global__ __launch_bounds__(64, 4) void gemm1(const uint32_t* __restrict__ sbits,
                                               const float* __restrict__ Wt,
                                               float* __restrict__ a1) {
  __shared__ float sW[32][64];   // [k][n] 8 KB
  __shared__ uint32_t sA[64];    // one k-block of bits per m-row
  const int tid = threadIdx.x;
  const int tx = tid & 7;   // n
  const int ty = tid >> 3;  // m
  const int m0 = blockIdx.x * 64;
  const int n0 = blockIdx.y * 64;
  float acc[8][8] = {};
  const float4* Wt4 = (const float4*)Wt;
  for (int kb = 0; kb < KW; ++kb) {
    __syncthreads();
    sA[tid] = sbits[(m0 + tid) * KW + kb];
#pragma unroll
    for (int r = 0; r < 8; ++r) {
      int idx = tid + r * 64;  // 0..511 float4s
      int k = idx >> 4;        // 0..31
      int q = idx & 15;        // 0..15
      float4 v = Wt4[(kb * 32 + k) * (N_PAD / 4) + (n0 >> 2) + q];
      *(float4*)&sW[k][q * 4] = v;
    }
    __syncthreads();
    uint4 aw0 = *(const uint4*)&sA[ty * 8];
    uint4 aw1 = *(const uint4*)&sA[ty * 8 + 4];
#pragma unroll 8
    for (int k = 0; k < 32; ++k) {
      float4 b0 = *(const float4*)&sW[k][tx * 8];
      float4 b1 = *(const float4*)&sW[k][tx * 8 + 4];
      float bv[8] = {b0.x, b0.y, b0.z, b0.w, b1.x, b1.y, b1.z, b1.w};
      float av[8];
      av[0] = (float)((aw0.x >> k) & 1u);
      av[1] = (float)((aw0.y >> k) & 1u);
      av[2] = (float)((aw0.z >> k) & 1u);
      av[3] = (float)((aw0.w >> k) & 1u);
      av[4] = (float)((aw1.x >> k) & 1u);
      av[5] = (float)((aw1.y >> k) & 1u);
      av[6] = (float)((aw1.z >> k) & 1u);
      av[7] = (float)((aw1.w >> k) & 1u);
#pragma unroll
      for (int i = 0; i < 8; ++i)
#pragma unroll
        for (int jj = 0; jj < 8; ++jj)
          acc[i][jj] = fmaf(av[i], bv[jj], acc[i][jj]);
    }
  }
#pragma unroll
  for (int i = 0; i < 8; ++i) {
    float* row = a1 + (m0 + ty * 8 + i) * N_PAD + n0 + tx * 8;
    *(float4*)row = make_float4(acc[i][0], acc[i][1], acc[i][2], acc[i][3]);
    *(float4*)(row + 4) = make_float4(acc[i][4], acc[i][5], acc[i][6], acc[i][7]);
  }
}

// u[t] = decay*u[t-1] + a1[t]; s1 = (u >= 10). mul+add kept separate (XLA
// does not contract to fma) via __fmul_rn/__fadd_rn.
__global__ __launch_bounds__(256) void psp_spike1(const float* __restrict__ a1,
                                                  float* __restrict__ s1) {
  int t = blockIdx.x * 256 + threadIdx.x;  // 32*416 = 13312
  int b = t / 416;
  int o = t % 416;
  if (b >= B_SZ || o >= F_HID) return;
  float u = 0.0f;
  const float* p = a1 + b * T_SZ * N_PAD + o;
  float* q = s1 + b * T_SZ * N_PAD + o;
  for (int tt = 0; tt < T_SZ; ++tt) {
    u = __fadd_rn(__fmul_rn(DECAY, u), p[tt * N_PAD]);
    q[tt * N_PAD] = (u >= THETA) ? 1.0f : 0.0f;
  }
}

// a2[m][o] = sum_h s1[m][h] * W2[o][h] — one wave per m-row
__global__ __launch_bounds__(256) void gemm2(const float* __restrict__ s1,
                                             const float* __restrict__ W2,
                                             float* __restrict__ a2) {
  int g = blockIdx.x * 256 + threadIdx.x;
  int m = g >> 6;
  int lane = g & 63;
  if (m >= M_SZ) return;
  const float* row = s1 + m * N_PAD;
  float p[F_OUT];
#pragma unroll
  for (int o = 0; o < F_OUT; ++o) p[o] = 0.0f;
  for (int h = lane; h < F_HID; h += 64) {
    float sv = row[h];
#pragma unroll
    for (int o = 0; o < F_OUT; ++o) p[o] = fmaf(sv, W2[o * F_HID + h], p[o]);
  }
#pragma unroll
  for (int o = 0; o < F_OUT; ++o) {
    float v = p[o];
#pragma unroll
    for (int s = 32; s > 0; s >>= 1) v += __shfl_down(v, s, 64);
    if (lane == 0) a2[m * A2_STRIDE + o] = v;
  }
}

// Final PSP + threshold + [B,10,T] transpose write
__global__ __launch_bounds__(256) void psp_spike2(const float* __restrict__ a2,
                                                  float* __restrict__ out) {
  int t = blockIdx.x * 256 + threadIdx.x;
  if (t >= B_SZ * F_OUT) return;
  int b = t / F_OUT;
  int o = t % F_OUT;
  float u = 0.0f;
  const float* p = a2 + b * T_SZ * A2_STRIDE + o;
  float* q = out + b * F_OUT * T_SZ + o * T_SZ;
  for (int tt = 0; tt < T_SZ; ++tt) {
    u = __fadd_rn(__fmul_rn(DECAY, u), p[tt * A2_STRIDE]);
    q[tt] = (u >= THETA) ? 1.0f : 0.0f;
  }
}

extern "C" void kernel_launch(void* const* d_in, const int* in_sizes, int n_in,
                              void* d_out, int out_size, void* d_ws, size_t ws_size,
                              hipStream_t stream) {
  const float* inp = (const float*)d_in[0];  // [32,3,32,32]
  const float* W1  = (const float*)d_in[1];  // [410,3072]
  const float* W2  = (const float*)d_in[2];  // [10,410]
  float* out = (float*)d_out;                // [32,10,300]
  char* ws = (char*)d_ws;
  // ws layout (bytes): Wt 6291456 | sbits 3686400 | a1 19660800 | s1 19660800 | a2 614400
  float*    Wt    = (float*)(ws);
  uint32_t* sbits = (uint32_t*)(ws + 6291456);
  float*    a1    = (float*)(ws + 6291456 + 3686400);
  float*    s1    = a1 + (size_t)M_SZ * N_PAD;
  float*    a2    = s1 + (size_t)M_SZ * N_PAD;

  transpose_w1<<<dim3(96, 16), dim3(256), 0, stream>>>(W1, Wt);
#if THREEFRY_PARTITIONABLE
  rng_spikes<<<dim3(N_WORDS / 256), dim3(256), 0, stream>>>(inp, sbits);
#else
  rng_spikes<<<dim3((HALF_N / 32) / 256), dim3(256), 0, stream>>>(inp, sbits);
#endif
  gemm1<<<dim3(M_SZ / 64, N_PAD / 64), dim3(64), 0, stream>>>(sbits, Wt, a1);
  psp_spike1<<<dim3((B_SZ * 416) / 256), dim3(256), 0, stream>>>(a1, s1);
  gemm2<<<dim3((M_SZ * 64) / 256), dim3(256), 0, stream>>>(s1, W2, a2);
  psp_spike2<<<dim3(2), dim3(256), 0, stream>>>(a2, out);
}

// Round 2
// 261.830 us; speedup vs baseline: 3.3879x; 3.3879x over previous
//
#include <hip/hip_runtime.h>
#include <stdint.h>

#define B_SZ 32
#define T_SZ 300
#define F_IN 3072
#define F_HID 410
#define F_OUT 10
#define M_SZ (B_SZ * T_SZ)              // 9600
#define N_PAD 448                       // padded hidden width (7 x 64)
#define KW (F_IN / 32)                  // 96 bit-words per spike row
#define TOTAL_ELEMS (B_SZ * T_SZ * F_IN)  // 29491200
#define N_WORDS (TOTAL_ELEMS / 32)        // 921600
#define A2_STRIDE 16

// f32(exp(f32(-0.1))) — PSP decay, matches XLA's correctly-rounded exp
#define DECAY 0.90483741803595957f
#define THETA 10.0f

typedef __attribute__((ext_vector_type(8))) short bf16x8;
typedef __attribute__((ext_vector_type(4))) float f32x4;

__device__ __forceinline__ uint32_t rotl32(uint32_t x, uint32_t r) {
  return (x << r) | (x >> (32u - r));
}

// JAX threefry2x32, key = (0, 42)
__device__ __forceinline__ void threefry2x32(uint32_t& x0, uint32_t& x1) {
  const uint32_t ks0 = 0u;
  const uint32_t ks1 = 42u;
  const uint32_t ks2 = 0x1BD11BDAu ^ 0u ^ 42u;
  x0 += ks0; x1 += ks1;
#define TF_ROUND(r) { x0 += x1; x1 = rotl32(x1, (r)); x1 ^= x0; }
  TF_ROUND(13) TF_ROUND(15) TF_ROUND(26) TF_ROUND(6)
  x0 += ks1; x1 += ks2 + 1u;
  TF_ROUND(17) TF_ROUND(29) TF_ROUND(16) TF_ROUND(24)
  x0 += ks2; x1 += ks0 + 2u;
  TF_ROUND(13) TF_ROUND(15) TF_ROUND(26) TF_ROUND(6)
  x0 += ks0; x1 += ks1 + 3u;
  TF_ROUND(17) TF_ROUND(29) TF_ROUND(16) TF_ROUND(24)
  x0 += ks1; x1 += ks2 + 4u;
  TF_ROUND(13) TF_ROUND(15) TF_ROUND(26) TF_ROUND(6)
  x0 += ks2; x1 += ks0 + 5u;
#undef TF_ROUND
}

__device__ __forceinline__ float u01(uint32_t bits) {
  return __uint_as_float((bits >> 9) | 0x3F800000u) - 1.0f;
}

// Partitionable threefry: ctr=(0,i), bits = o0^o1. One thread per 32-bit word.
__global__ __launch_bounds__(256) void rng_spikes(const float* __restrict__ inp,
                                                  uint32_t* __restrict__ sbits) {
  uint32_t j = blockIdx.x * 256u + threadIdx.x;  // [0, 921600)
  uint32_t base = j << 5;
  uint32_t b = base / (uint32_t)(T_SZ * F_IN);
  uint32_t f = base % (uint32_t)F_IN;
  const float* p = inp + b * F_IN + f;
  float pr[32];
#pragma unroll
  for (int q = 0; q < 8; ++q) {
    float4 v = ((const float4*)p)[q];
    pr[q * 4 + 0] = v.x; pr[q * 4 + 1] = v.y; pr[q * 4 + 2] = v.z; pr[q * 4 + 3] = v.w;
  }
  uint32_t w = 0u;
#pragma unroll
  for (uint32_t k = 0; k < 32u; ++k) {
    uint32_t x0 = 0u, x1 = base + k;
    threefry2x32(x0, x1);
    float u = u01(x0 ^ x1);
    w |= (u < pr[k]) ? (1u << k) : 0u;
  }
  sbits[j] = w;
}

// W1 fp32 [410][3072] -> W1b bf16 (RTNE) [448][3072], rows >= 410 zeroed.
__global__ __launch_bounds__(256) void w1_to_bf16(const float* __restrict__ W1,
                                                  unsigned short* __restrict__ W1b) {
  int idx = blockIdx.x * 256 + threadIdx.x;   // 448*3072/8 = 172032 threads
  int g = idx * 8;
  int row = g / F_IN;
  int col = g - row * F_IN;
  uint32_t d[4];
  if (row < F_HID) {
    const float* s = W1 + row * F_IN + col;
    float4 v0 = ((const float4*)s)[0];
    float4 v1 = ((const float4*)s)[1];
    float vv[8] = {v0.x, v0.y, v0.z, v0.w, v1.x, v1.y, v1.z, v1.w};
#pragma unroll
    for (int q = 0; q < 4; ++q) {
      uint32_t u0 = __float_as_uint(vv[q * 2]);
      uint32_t u1 = __float_as_uint(vv[q * 2 + 1]);
      uint32_t h0 = (u0 + 0x7FFFu + ((u0 >> 16) & 1u)) >> 16;
      uint32_t h1 = (u1 + 0x7FFFu + ((u1 >> 16) & 1u)) >> 16;
      d[q] = h0 | (h1 << 16);
    }
  } else {
    d[0] = d[1] = d[2] = d[3] = 0u;
  }
  *(uint4*)(W1b + row * F_IN + col) = make_uint4(d[0], d[1], d[2], d[3]);
}

// a1[m][n] = sum_k spike(m,k) * W1[n][k]  — bf16 MFMA 16x16x32.
// BM=128, BN=64, BK=64. 256 threads = 4 waves, wave tile 64x32.
// A bits expanded to bf16 in LDS; B = W1b rows copied to LDS (both [row][k], stride 72).
__global__ __launch_bounds__(256) void gemm1(const uint32_t* __restrict__ sbits,
                                             const unsigned short* __restrict__ W1b,
                                             float* __restrict__ a1) {
  __shared__ short As[128][72];  // 18.4 KB  (pad 72: 2-way-bank-free b128 reads)
  __shared__ short Bs[64][72];   //  9.2 KB
  const int tid = threadIdx.x;
  const int m0 = blockIdx.x * 128;
  const int n0 = blockIdx.y * 64;
  const int wave = tid >> 6;
  const int lane = tid & 63;
  const int lr = lane & 15;        // frag row (m or n)
  const int lc = lane >> 4;        // k-chunk / output quad
  const int wm = (wave >> 1) * 64; // wave m-offset within block
  const int wn = (wave & 1) * 32;  // wave n-offset within block

  const int arow = tid >> 1;       // A-staging: 128 rows x 2 words
  const int awsel = tid & 1;

  f32x4 acc[4][2];
#pragma unroll
  for (int i = 0; i < 4; ++i)
#pragma unroll
    for (int j = 0; j < 2; ++j)
      acc[i][j] = (f32x4){0.f, 0.f, 0.f, 0.f};

  for (int kb = 0; kb < F_IN / 64; ++kb) {
    __syncthreads();
    // --- stage A: bitpacked -> bf16 LDS
    {
      uint32_t w = sbits[(m0 + arow) * KW + kb * 2 + awsel];
#pragma unroll
      for (int q = 0; q < 4; ++q) {
        uint4 u;
        u.x = ((w >> (q * 8 + 0)) & 1u) * 0x3F80u | ((w >> (q * 8 + 1)) & 1u) * 0x3F800000u;
        u.y = ((w >> (q * 8 + 2)) & 1u) * 0x3F80u | ((w >> (q * 8 + 3)) & 1u) * 0x3F800000u;
        u.z = ((w >> (q * 8 + 4)) & 1u) * 0x3F80u | ((w >> (q * 8 + 5)) & 1u) * 0x3F800000u;
        u.w = ((w >> (q * 8 + 6)) & 1u) * 0x3F80u | ((w >> (q * 8 + 7)) & 1u) * 0x3F800000u;
        *(uint4*)&As[arow][awsel * 32 + q * 8] = u;
      }
    }
    // --- stage B: 64 rows x 64 bf16 (128 B per row)
#pragma unroll
    for (int q = 0; q < 2; ++q) {
      int idx = tid + q * 256;
      int row = idx >> 3;
      int c = idx & 7;
      uint4 v = *(const uint4*)(W1b + (size_t)(n0 + row) * F_IN + kb * 64 + c * 8);
      *(uint4*)&Bs[row][c * 8] = v;
    }
    __syncthreads();
    // --- MFMA over 2 k-substeps of 32
#pragma unroll
    for (int sub = 0; sub < 2; ++sub) {
      int kk = sub * 32 + lc * 8;
      bf16x8 bfr[2];
#pragma unroll
      for (int nt = 0; nt < 2; ++nt)
        bfr[nt] = *(bf16x8*)&Bs[wn + nt * 16 + lr][kk];
#pragma unroll
      for (int mt = 0; mt < 4; ++mt) {
        bf16x8 afr = *(bf16x8*)&As[wm + mt * 16 + lr][kk];
#pragma unroll
        for (int nt = 0; nt < 2; ++nt)
          acc[mt][nt] = __builtin_amdgcn_mfma_f32_16x16x32_bf16(afr, bfr[nt], acc[mt][nt], 0, 0, 0);
      }
    }
  }
  // epilogue: row = quad*4 + reg (m), col = lane&15 (n)
#pragma unroll
  for (int mt = 0; mt < 4; ++mt)
#pragma unroll
    for (int nt = 0; nt < 2; ++nt) {
      int col = n0 + wn + nt * 16 + lr;
#pragma unroll
      for (int r = 0; r < 4; ++r) {
        int row = m0 + wm + mt * 16 + lc * 4 + r;
        a1[(size_t)row * N_PAD + col] = acc[mt][nt][r];
      }
    }
}

// u[t] = decay*u[t-1] + a1[t]; s1 = (u >= 10).
__global__ __launch_bounds__(256) void psp_spike1(const float* __restrict__ a1,
                                                  float* __restrict__ s1) {
  int t = blockIdx.x * 256 + threadIdx.x;  // 32*448 = 14336
  int b = t / N_PAD;
  int o = t % N_PAD;
  if (b >= B_SZ || o >= F_HID) return;
  float u = 0.0f;
  const float* p = a1 + (size_t)b * T_SZ * N_PAD + o;
  float* q = s1 + (size_t)b * T_SZ * N_PAD + o;
  for (int tt = 0; tt < T_SZ; ++tt) {
    u = __fadd_rn(__fmul_rn(DECAY, u), p[(size_t)tt * N_PAD]);
    q[(size_t)tt * N_PAD] = (u >= THETA) ? 1.0f : 0.0f;
  }
}

// a2[m][o] = sum_h s1[m][h] * W2[o][h] — one wave per m-row
__global__ __launch_bounds__(256) void gemm2(const float* __restrict__ s1,
                                             const float* __restrict__ W2,
                                             float* __restrict__ a2) {
  int g = blockIdx.x * 256 + threadIdx.x;
  int m = g >> 6;
  int lane = g & 63;
  if (m >= M_SZ) return;
  const float* row = s1 + (size_t)m * N_PAD;
  float p[F_OUT];
#pragma unroll
  for (int o = 0; o < F_OUT; ++o) p[o] = 0.0f;
  for (int h = lane; h < F_HID; h += 64) {
    float sv = row[h];
#pragma unroll
    for (int o = 0; o < F_OUT; ++o) p[o] = fmaf(sv, W2[o * F_HID + h], p[o]);
  }
#pragma unroll
  for (int o = 0; o < F_OUT; ++o) {
    float v = p[o];
#pragma unroll
    for (int s = 32; s > 0; s >>= 1) v += __shfl_down(v, s, 64);
    if (lane == 0) a2[m * A2_STRIDE + o] = v;
  }
}

// Final PSP + threshold + [B,10,T] transpose write
__global__ __launch_bounds__(256) void psp_spike2(const float* __restrict__ a2,
                                                  float* __restrict__ out) {
  int t = blockIdx.x * 256 + threadIdx.x;
  if (t >= B_SZ * F_OUT) return;
  int b = t / F_OUT;
  int o = t % F_OUT;
  float u = 0.0f;
  const float* p = a2 + (size_t)b * T_SZ * A2_STRIDE + o;
  float* q = out + (size_t)b * F_OUT * T_SZ + (size_t)o * T_SZ;
  for (int tt = 0; tt < T_SZ; ++tt) {
    u = __fadd_rn(__fmul_rn(DECAY, u), p[(size_t)tt * A2_STRIDE]);
    q[tt] = (u >= THETA) ? 1.0f : 0.0f;
  }
}

extern "C" void kernel_launch(void* const* d_in, const int* in_sizes, int n_in,
                              void* d_out, int out_size, void* d_ws, size_t ws_size,
                              hipStream_t stream) {
  const float* inp = (const float*)d_in[0];  // [32,3,32,32]
  const float* W1  = (const float*)d_in[1];  // [410,3072]
  const float* W2  = (const float*)d_in[2];  // [10,410]
  float* out = (float*)d_out;                // [32,10,300]
  char* ws = (char*)d_ws;
  // ws: W1b 2752512 | sbits 3686400 | a1 17203200 | s1 17203200 | a2 614400  (~41.5 MB)
  unsigned short* W1b = (unsigned short*)(ws);
  uint32_t* sbits = (uint32_t*)(ws + 2752512);
  float* a1 = (float*)(ws + 2752512 + 3686400);
  float* s1 = a1 + (size_t)M_SZ * N_PAD;
  float* a2 = s1 + (size_t)M_SZ * N_PAD;

  w1_to_bf16<<<dim3((N_PAD * F_IN / 8) / 256), dim3(256), 0, stream>>>(W1, W1b);
  rng_spikes<<<dim3(N_WORDS / 256), dim3(256), 0, stream>>>(inp, sbits);
  gemm1<<<dim3(M_SZ / 128, N_PAD / 64), dim3(256), 0, stream>>>(sbits, W1b, a1);
  psp_spike1<<<dim3((B_SZ * N_PAD) / 256), dim3(256), 0, stream>>>(a1, s1);
  gemm2<<<dim3((M_SZ * 64) / 256), dim3(256), 0, stream>>>(s1, W2, a2);
  psp_spike2<<<dim3(2), dim3(256), 0, stream>>>(a2, out);
}